// Round 4
// baseline (473.485 us; speedup 1.0000x reference)
//
#include <hip/hip_runtime.h>
#include <hip/hip_bf16.h>

#define N_PTS 100000
#define KOFF 343
#define EPS 1e-5f
#define NTILES 3125   // N_PTS / 32

typedef __hip_bfloat16 bf16;
typedef __attribute__((ext_vector_type(4))) float f32x4;
typedef __attribute__((ext_vector_type(16))) float f32x16;
typedef __attribute__((ext_vector_type(8))) short s16x8;

// ---------------- pack: w_conv [343][32][32] f32 -> bf16 B-fragments ----------------
// wpk layout: [k][s][lane][j], element = w_conv[k][s*16 + (lane>>5)*8 + j][lane&31]
__global__ __launch_bounds__(256) void pack_kernel(const float* __restrict__ w_conv,
                                                   bf16* __restrict__ wpk) {
  int t = blockIdx.x * 256 + threadIdx.x;
  if (t >= KOFF * 128) return;
  int l = t & 63;
  int s = (t >> 6) & 1;
  int k = t >> 7;
  int col = l & 31;
  int kq = l >> 5;
  const float* wk = w_conv + k * 1024;
  s16x8 v;
  for (int j = 0; j < 8; ++j) {
    bf16 h = __float2bfloat16(wk[(s * 16 + kq * 8 + j) * 32 + col]);
    short sv;
    __builtin_memcpy(&sv, &h, 2);
    v[j] = sv;
  }
  *reinterpret_cast<s16x8*>(reinterpret_cast<char*>(wpk) + (size_t)t * 16) = v;
}

// ---------------- unary1: h1b = bf16( LN(feats @ w1) )  [N,32] ----------------
__global__ __launch_bounds__(256) void unary1_kernel(const float* __restrict__ feats,
    const float* __restrict__ w1, const float* __restrict__ g1,
    const float* __restrict__ b1, bf16* __restrict__ h1b) {
  __shared__ float sf[8][128];
  __shared__ float sw[128 * 32];
  int tid = threadIdx.x;
  int rbase = blockIdx.x * 8;
  for (int i = tid; i < 1024; i += 256)
    reinterpret_cast<f32x4*>(sw)[i] = reinterpret_cast<const f32x4*>(w1)[i];
  {
    int i = tid;
    int r = rbase + (i >> 5);
    f32x4 v = reinterpret_cast<const f32x4*>(feats)[(size_t)r * 32 + (i & 31)];
    reinterpret_cast<f32x4*>(&sf[0][0])[i] = v;
  }
  __syncthreads();
  int half = tid >> 5;
  int c = tid & 31;
  int r = rbase + half;
  const float* frow = sf[half];
  float acc = 0.f;
  #pragma unroll 8
  for (int kk = 0; kk < 128; ++kk)
    acc += frow[kk] * sw[kk * 32 + c];
  float s = acc, s2 = acc * acc;
  #pragma unroll
  for (int m = 16; m >= 1; m >>= 1) {
    s  += __shfl_xor(s,  m, 64);
    s2 += __shfl_xor(s2, m, 64);
  }
  float mean = s * (1.f / 32.f);
  float var  = s2 * (1.f / 32.f) - mean * mean;
  float y = (acc - mean) * rsqrtf(var + EPS) * g1[c] + b1[c];
  h1b[(size_t)r * 32 + c] = __float2bfloat16(y);
}

// ---------------- transpose: nbr [N][343] -> nbrT [343][N] ----------------
// 32x32 tiles via LDS, both sides coalesced. grid (3125, 11)
__global__ __launch_bounds__(256) void transpose_kernel(const int* __restrict__ nbr,
                                                        int* __restrict__ nbrT) {
  __shared__ int t[32][33];
  int tx = threadIdx.x & 31;
  int ty0 = threadIdx.x >> 5;
  int n0 = blockIdx.x * 32;
  int k0 = blockIdx.y * 32;
  #pragma unroll
  for (int q = 0; q < 4; ++q) {
    int ty = ty0 + 8 * q;
    int k = k0 + tx;
    if (k < KOFF) t[ty][tx] = nbr[(size_t)(n0 + ty) * KOFF + k];
  }
  __syncthreads();
  #pragma unroll
  for (int q = 0; q < 4; ++q) {
    int ky = ty0 + 8 * q;
    if (k0 + ky < KOFF)
      nbrT[(size_t)(k0 + ky) * N_PTS + n0 + tx] = t[tx][ky];
  }
}

// ---------------- conv (transposed-nbr path): zero LDS, wave = one 32-pt tile ----------------
// idx loads coalesced from nbrT (one 128B line / wave / k), software-pipelined one
// chunk (4 offsets) ahead; 4 waves per block walk the same k -> wpk B-lines L1-hit.
// A-frag: row=lane&31, k-chunk kq=lane>>5; D: col=lane&31, row=(reg&3)+8*(reg>>2)+4*kq
__global__ __launch_bounds__(256) void conv_t_kernel(const bf16* __restrict__ h1b,
    const int* __restrict__ nbrT, const bf16* __restrict__ wpk,
    float* __restrict__ h2) {
  int tid = threadIdx.x;
  int wave = tid >> 6;
  int l = tid & 63;
  int col = l & 31;
  int kq = l >> 5;
  int tile = blockIdx.x * 4 + wave;
  if (tile >= NTILES) return;
  int pbase = tile * 32;
  const int* nbase = nbrT + pbase + col;
  f32x16 acc;
  #pragma unroll
  for (int i = 0; i < 16; ++i) acc[i] = 0.f;
  const s16x8* wb = reinterpret_cast<const s16x8*>(wpk);
  const s16x8 zv = {0, 0, 0, 0, 0, 0, 0, 0};
  int idc[4];
  #pragma unroll
  for (int j = 0; j < 4; ++j) idc[j] = nbase[(size_t)j * N_PTS];
  for (int kb = 0; kb < KOFF; kb += 4) {
    // prefetch next chunk's indices (breaks the idx->gather->MFMA chain)
    int idn[4];
    #pragma unroll
    for (int j = 0; j < 4; ++j) {
      int kn = kb + 4 + j;
      idn[j] = (kn < KOFF) ? nbase[(size_t)kn * N_PTS] : -1;
    }
    s16x8 A0[4], A1[4], B0[4], B1[4];
    #pragma unroll
    for (int j = 0; j < 4; ++j) {
      int k = kb + j;
      int kc = (k < KOFF) ? k : (KOFF - 1);
      int id = (k < KOFF) ? idc[j] : -1;
      const s16x8* r = reinterpret_cast<const s16x8*>(h1b + (size_t)(id < 0 ? 0 : id) * 32);
      A0[j] = r[kq];
      A1[j] = r[2 + kq];
      B0[j] = wb[(size_t)kc * 128 + l];
      B1[j] = wb[(size_t)kc * 128 + 64 + l];
    }
    #pragma unroll
    for (int j = 0; j < 4; ++j) {
      int k = kb + j;
      int id = (k < KOFF) ? idc[j] : -1;
      s16x8 a0 = id < 0 ? zv : A0[j];
      s16x8 a1 = id < 0 ? zv : A1[j];
      acc = __builtin_amdgcn_mfma_f32_32x32x16_bf16(a0, B0[j], acc, 0, 0, 0);
      acc = __builtin_amdgcn_mfma_f32_32x32x16_bf16(a1, B1[j], acc, 0, 0, 0);
    }
    #pragma unroll
    for (int j = 0; j < 4; ++j) idc[j] = idn[j];
  }
  #pragma unroll
  for (int reg = 0; reg < 16; ++reg) {
    int rrow = (reg & 3) + 8 * (reg >> 2) + 4 * kq;
    h2[(size_t)(pbase + rrow) * 32 + col] = acc[reg];
  }
}

// ---------------- conv (fallback, LDS-staged nbr; same as R3) ----------------
__global__ __launch_bounds__(256) void conv_kernel(const bf16* __restrict__ h1b,
    const int* __restrict__ nbr, const bf16* __restrict__ wpk,
    float* __restrict__ h2) {
  __shared__ int snbr[32 * 345];
  int tid = threadIdx.x;
  int wave = tid >> 6;
  int l = tid & 63;
  int col = l & 31;
  int kq = l >> 5;
  int pbase = blockIdx.x * 32;
  {
    const int* g = nbr + (size_t)pbase * KOFF;
    for (int i = tid; i < 32 * KOFF; i += 256) {
      unsigned row = (unsigned)i / KOFF;
      unsigned kk = (unsigned)i - row * KOFF;
      snbr[row * 345 + kk] = g[i];
    }
  }
  __syncthreads();
  int k0 = (KOFF * wave) >> 2;
  int k1 = (KOFF * (wave + 1)) >> 2;
  f32x16 acc;
  #pragma unroll
  for (int i = 0; i < 16; ++i) acc[i] = 0.f;
  const s16x8* wb = reinterpret_cast<const s16x8*>(wpk);
  const s16x8 zv = {0, 0, 0, 0, 0, 0, 0, 0};
  const int* myrow = snbr + col * 345;
  for (int kb = k0; kb < k1; kb += 4) {
    int id[4];
    s16x8 A0[4], A1[4], B0[4], B1[4];
    #pragma unroll
    for (int j = 0; j < 4; ++j) {
      int k = kb + j;
      id[j] = (k < k1) ? myrow[k] : -1;
    }
    #pragma unroll
    for (int j = 0; j < 4; ++j) {
      int k = kb + j;
      int kc = (k < k1) ? k : (k1 - 1);
      const s16x8* r = reinterpret_cast<const s16x8*>(h1b + (size_t)(id[j] < 0 ? 0 : id[j]) * 32);
      A0[j] = r[kq];
      A1[j] = r[2 + kq];
      B0[j] = wb[(size_t)kc * 128 + l];
      B1[j] = wb[(size_t)kc * 128 + 64 + l];
    }
    #pragma unroll
    for (int j = 0; j < 4; ++j) {
      s16x8 a0 = id[j] < 0 ? zv : A0[j];
      s16x8 a1 = id[j] < 0 ? zv : A1[j];
      acc = __builtin_amdgcn_mfma_f32_32x32x16_bf16(a0, B0[j], acc, 0, 0, 0);
      acc = __builtin_amdgcn_mfma_f32_32x32x16_bf16(a1, B1[j], acc, 0, 0, 0);
    }
  }
  __syncthreads();
  float* red = reinterpret_cast<float*>(snbr);
  #pragma unroll
  for (int reg = 0; reg < 16; ++reg) {
    int rrow = (reg & 3) + 8 * (reg >> 2) + 4 * kq;
    red[wave * 1024 + rrow * 32 + col] = acc[reg];
  }
  __syncthreads();
  const f32x4* rv = reinterpret_cast<const f32x4*>(red);
  f32x4 s = rv[tid] + rv[256 + tid] + rv[512 + tid] + rv[768 + tid];
  reinterpret_cast<f32x4*>(h2 + (size_t)pbase * 32)[tid] = s;
}

// ---------------- unary2: out = gelu(LN(h2 @ w2)) + feats  [N,128] f32 ----------------
__global__ __launch_bounds__(256) void unary2_kernel(const float* __restrict__ h2,
    const float* __restrict__ w2, const float* __restrict__ g2,
    const float* __restrict__ b2, const float* __restrict__ feats,
    float* __restrict__ out) {
  int tid = threadIdx.x;
  int wave = tid >> 6;
  int l = tid & 63;
  int r = blockIdx.x * 4 + wave;
  const float* hrow = h2 + (size_t)r * 32;
  float acc0 = 0.f, acc1 = 0.f;
  #pragma unroll
  for (int q = 0; q < 8; ++q) {
    f32x4 hv = reinterpret_cast<const f32x4*>(hrow)[q];
    #pragma unroll
    for (int j = 0; j < 4; ++j) {
      int kk = q * 4 + j;
      float h = hv[j];
      acc0 += h * w2[kk * 128 + l];
      acc1 += h * w2[kk * 128 + 64 + l];
    }
  }
  float s = acc0 + acc1, s2 = acc0 * acc0 + acc1 * acc1;
  #pragma unroll
  for (int m = 32; m >= 1; m >>= 1) {
    s  += __shfl_xor(s,  m, 64);
    s2 += __shfl_xor(s2, m, 64);
  }
  float mean = s * (1.f / 128.f);
  float var  = s2 * (1.f / 128.f) - mean * mean;
  float inv = rsqrtf(var + EPS);
  float y0 = (acc0 - mean) * inv * g2[l] + b2[l];
  float y1 = (acc1 - mean) * inv * g2[64 + l] + b2[64 + l];
  float ge0 = 0.5f * y0 * (1.f + erff(y0 * 0.70710678118f));
  float ge1 = 0.5f * y1 * (1.f + erff(y1 * 0.70710678118f));
  out[(size_t)r * 128 + l]      = ge0 + feats[(size_t)r * 128 + l];
  out[(size_t)r * 128 + 64 + l] = ge1 + feats[(size_t)r * 128 + 64 + l];
}

extern "C" void kernel_launch(void* const* d_in, const int* in_sizes, int n_in,
                              void* d_out, int out_size, void* d_ws, size_t ws_size,
                              hipStream_t stream) {
  const float* feats  = (const float*)d_in[0];
  const int*   nbr    = (const int*)d_in[1];
  const float* w1     = (const float*)d_in[2];
  const float* ln1_g  = (const float*)d_in[3];
  const float* ln1_b  = (const float*)d_in[4];
  const float* w_conv = (const float*)d_in[5];
  const float* w2     = (const float*)d_in[6];
  const float* ln2_g  = (const float*)d_in[7];
  const float* ln2_b  = (const float*)d_in[8];
  float* out = (float*)d_out;
  char* ws = (char*)d_ws;
  bf16*  h1b = (bf16*)ws;                    // 100000*32*2  = 6,400,000 B
  bf16*  wpk = (bf16*)(ws + 6400000);        // 343*128*16   =   702,464 B
  float* h2  = (float*)(ws + 7102464);       // 100000*32*4  = 12,800,000 B
  int*   nbrT = (int*)(ws + 19902464);       // 343*100000*4 = 137,200,000 B
  const size_t need = 19902464ULL + 137200000ULL;

  hipLaunchKernelGGL(pack_kernel,   dim3((KOFF * 128 + 255) / 256), dim3(256), 0, stream, w_conv, wpk);
  hipLaunchKernelGGL(unary1_kernel, dim3(N_PTS / 8),                dim3(256), 0, stream, feats, w1, ln1_g, ln1_b, h1b);
  if (ws_size >= need) {
    hipLaunchKernelGGL(transpose_kernel, dim3(NTILES, (KOFF + 31) / 32), dim3(256), 0, stream, nbr, nbrT);
    hipLaunchKernelGGL(conv_t_kernel,    dim3((NTILES + 3) / 4),         dim3(256), 0, stream, h1b, nbrT, wpk, h2);
  } else {
    hipLaunchKernelGGL(conv_kernel,      dim3(NTILES),                   dim3(256), 0, stream, h1b, nbr, wpk, h2);
  }
  hipLaunchKernelGGL(unary2_kernel, dim3(N_PTS / 4), dim3(256), 0, stream, h2, w2, ln2_g, ln2_b, feats, out);
}

// Round 5
// 455.843 us; speedup vs baseline: 1.0387x; 1.0387x over previous
//
#include <hip/hip_runtime.h>
#include <hip/hip_bf16.h>

#define N_PTS 100000
#define KOFF 343
#define EPS 1e-5f
#define NTILES 3125   // N_PTS / 32

typedef __hip_bfloat16 bf16;
typedef __attribute__((ext_vector_type(4))) float f32x4;
typedef __attribute__((ext_vector_type(16))) float f32x16;
typedef __attribute__((ext_vector_type(8))) short s16x8;

// ---------------- pack: w_conv [343][32][32] f32 -> bf16 B-fragments ----------------
// wpk layout: [k][s][lane][j], element = w_conv[k][s*16 + (lane>>5)*8 + j][lane&31]
__global__ __launch_bounds__(256) void pack_kernel(const float* __restrict__ w_conv,
                                                   bf16* __restrict__ wpk) {
  int t = blockIdx.x * 256 + threadIdx.x;
  if (t >= KOFF * 128) return;
  int l = t & 63;
  int s = (t >> 6) & 1;
  int k = t >> 7;
  int col = l & 31;
  int kq = l >> 5;
  const float* wk = w_conv + k * 1024;
  s16x8 v;
  for (int j = 0; j < 8; ++j) {
    bf16 h = __float2bfloat16(wk[(s * 16 + kq * 8 + j) * 32 + col]);
    short sv;
    __builtin_memcpy(&sv, &h, 2);
    v[j] = sv;
  }
  *reinterpret_cast<s16x8*>(reinterpret_cast<char*>(wpk) + (size_t)t * 16) = v;
}

// ---------------- unary1: h1b = bf16( LN(feats @ w1) )  [N,32] ----------------
__global__ __launch_bounds__(256) void unary1_kernel(const float* __restrict__ feats,
    const float* __restrict__ w1, const float* __restrict__ g1,
    const float* __restrict__ b1, bf16* __restrict__ h1b) {
  __shared__ float sf[8][128];
  __shared__ float sw[128 * 32];
  int tid = threadIdx.x;
  int rbase = blockIdx.x * 8;
  for (int i = tid; i < 1024; i += 256)
    reinterpret_cast<f32x4*>(sw)[i] = reinterpret_cast<const f32x4*>(w1)[i];
  {
    int i = tid;
    int r = rbase + (i >> 5);
    f32x4 v = reinterpret_cast<const f32x4*>(feats)[(size_t)r * 32 + (i & 31)];
    reinterpret_cast<f32x4*>(&sf[0][0])[i] = v;
  }
  __syncthreads();
  int half = tid >> 5;
  int c = tid & 31;
  int r = rbase + half;
  const float* frow = sf[half];
  float acc = 0.f;
  #pragma unroll 8
  for (int kk = 0; kk < 128; ++kk)
    acc += frow[kk] * sw[kk * 32 + c];
  float s = acc, s2 = acc * acc;
  #pragma unroll
  for (int m = 16; m >= 1; m >>= 1) {
    s  += __shfl_xor(s,  m, 64);
    s2 += __shfl_xor(s2, m, 64);
  }
  float mean = s * (1.f / 32.f);
  float var  = s2 * (1.f / 32.f) - mean * mean;
  float y = (acc - mean) * rsqrtf(var + EPS) * g1[c] + b1[c];
  h1b[(size_t)r * 32 + c] = __float2bfloat16(y);
}

// ---------------- transpose: nbr [N][343] -> nbrT [343][N], 32k x 128n tiles ----------------
__global__ __launch_bounds__(256) void transpose_kernel(const int* __restrict__ nbr,
                                                        int* __restrict__ nbrT) {
  __shared__ int t[32][129];
  int n0 = blockIdx.x * 128;
  int k0 = blockIdx.y * 32;
  int tx = threadIdx.x & 31;   // k within tile
  int ty = threadIdx.x >> 5;   // row group 0..7
  int kmax = KOFF - k0;        // <=32 valid k in this tile
  #pragma unroll
  for (int q = 0; q < 16; ++q) {
    int r = ty + 8 * q;        // 0..127
    int n = n0 + r;
    if (n < N_PTS && tx < kmax) t[tx][r] = nbr[(size_t)n * KOFF + k0 + tx];
  }
  __syncthreads();
  int wx = threadIdx.x & 127;
  int wy = threadIdx.x >> 7;   // 0..1
  #pragma unroll
  for (int q = 0; q < 16; ++q) {
    int kk = wy + 2 * q;       // 0..31
    int n = n0 + wx;
    if (kk < kmax && n < N_PTS) nbrT[(size_t)(k0 + kk) * N_PTS + n] = t[kk][wx];
  }
}

// ---------------- conv v2: block = 2 tiles x 2-way k-split (4 waves) ----------------
// wave w: tile = w&1 (32 pts), k-half = w>>1. Waves 0/2 and 1/3 share B-lines in L1.
// idx coalesced from nbrT, prefetched 4 ahead; chunk=2 offsets, single-buffered loads.
// A-frag: row=lane&31, k-chunk kq=lane>>5; D: col=lane&31, row=(reg&3)+8*(reg>>2)+4*kq
__global__ __launch_bounds__(256, 6) void conv_t2_kernel(const bf16* __restrict__ h1b,
    const int* __restrict__ nbrT, const bf16* __restrict__ wpk,
    float* __restrict__ h2) {
  __shared__ float red[4 * 1024];          // 16 KB
  int tid = threadIdx.x;
  int wave = tid >> 6;
  int l = tid & 63;
  int col = l & 31;
  int kq = l >> 5;
  int tile = wave & 1;
  int half = wave >> 1;
  int pbase = blockIdx.x * 64 + tile * 32;
  bool live = pbase < N_PTS;
  const int* nbase = nbrT + pbase + col;
  int k0 = (KOFF * half) >> 1;             // 0 or 171
  int k1 = (KOFF * (half + 1)) >> 1;       // 171 or 343
  f32x16 acc;
  #pragma unroll
  for (int i = 0; i < 16; ++i) acc[i] = 0.f;
  const s16x8* wb = reinterpret_cast<const s16x8*>(wpk);
  const s16x8 zv = {0, 0, 0, 0, 0, 0, 0, 0};
  // idx ring, 4 ahead (2 chunks)
  int id0 = live ? nbase[(size_t)k0 * N_PTS] : -1;
  int id1 = (live && k0 + 1 < k1) ? nbase[(size_t)(k0 + 1) * N_PTS] : -1;
  int id2 = (live && k0 + 2 < k1) ? nbase[(size_t)(k0 + 2) * N_PTS] : -1;
  int id3 = (live && k0 + 3 < k1) ? nbase[(size_t)(k0 + 3) * N_PTS] : -1;
  for (int kb = k0; kb < k1; kb += 2) {
    int kc1 = (kb + 1 < k1) ? kb + 1 : kb;
    const s16x8* r0 = reinterpret_cast<const s16x8*>(h1b + (size_t)(id0 < 0 ? 0 : id0) * 32);
    const s16x8* r1 = reinterpret_cast<const s16x8*>(h1b + (size_t)(id1 < 0 ? 0 : id1) * 32);
    s16x8 A00 = r0[kq], A01 = r0[2 + kq];
    s16x8 A10 = r1[kq], A11 = r1[2 + kq];
    s16x8 B00 = wb[(size_t)kb * 128 + l];
    s16x8 B01 = wb[(size_t)kb * 128 + 64 + l];
    s16x8 B10 = wb[(size_t)kc1 * 128 + l];
    s16x8 B11 = wb[(size_t)kc1 * 128 + 64 + l];
    // prefetch idx for chunk +2 (issued before the MFMAs' waitcnt)
    int id4 = (live && kb + 4 < k1) ? nbase[(size_t)(kb + 4) * N_PTS] : -1;
    int id5 = (live && kb + 5 < k1) ? nbase[(size_t)(kb + 5) * N_PTS] : -1;
    s16x8 a;
    a = id0 < 0 ? zv : A00; acc = __builtin_amdgcn_mfma_f32_32x32x16_bf16(a, B00, acc, 0, 0, 0);
    a = id0 < 0 ? zv : A01; acc = __builtin_amdgcn_mfma_f32_32x32x16_bf16(a, B01, acc, 0, 0, 0);
    a = id1 < 0 ? zv : A10; acc = __builtin_amdgcn_mfma_f32_32x32x16_bf16(a, B10, acc, 0, 0, 0);
    a = id1 < 0 ? zv : A11; acc = __builtin_amdgcn_mfma_f32_32x32x16_bf16(a, B11, acc, 0, 0, 0);
    id0 = id2; id1 = id3; id2 = id4; id3 = id5;
  }
  #pragma unroll
  for (int reg = 0; reg < 16; ++reg) {
    int rrow = (reg & 3) + 8 * (reg >> 2) + 4 * kq;
    red[wave * 1024 + rrow * 32 + col] = acc[reg];
  }
  __syncthreads();
  // tile0 = waves 0+2, tile1 = waves 1+3; block writes 64 rows = 2048 floats
  const f32x4* rv = reinterpret_cast<const f32x4*>(red);
  f32x4 sA = rv[tid] + rv[512 + tid];
  f32x4 sB = rv[256 + tid] + rv[768 + tid];
  f32x4* o = reinterpret_cast<f32x4*>(h2 + (size_t)blockIdx.x * 2048);
  int p0 = blockIdx.x * 64;
  if (p0 + 32 <= N_PTS) o[tid] = sA;
  if (p0 + 64 <= N_PTS) o[256 + tid] = sB;
}

// ---------------- conv (fallback, LDS-staged nbr; R3 version) ----------------
__global__ __launch_bounds__(256) void conv_kernel(const bf16* __restrict__ h1b,
    const int* __restrict__ nbr, const bf16* __restrict__ wpk,
    float* __restrict__ h2) {
  __shared__ int snbr[32 * 345];
  int tid = threadIdx.x;
  int wave = tid >> 6;
  int l = tid & 63;
  int col = l & 31;
  int kq = l >> 5;
  int pbase = blockIdx.x * 32;
  {
    const int* g = nbr + (size_t)pbase * KOFF;
    for (int i = tid; i < 32 * KOFF; i += 256) {
      unsigned row = (unsigned)i / KOFF;
      unsigned kk = (unsigned)i - row * KOFF;
      snbr[row * 345 + kk] = g[i];
    }
  }
  __syncthreads();
  int k0 = (KOFF * wave) >> 2;
  int k1 = (KOFF * (wave + 1)) >> 2;
  f32x16 acc;
  #pragma unroll
  for (int i = 0; i < 16; ++i) acc[i] = 0.f;
  const s16x8* wb = reinterpret_cast<const s16x8*>(wpk);
  const s16x8 zv = {0, 0, 0, 0, 0, 0, 0, 0};
  const int* myrow = snbr + col * 345;
  for (int kb = k0; kb < k1; kb += 4) {
    int id[4];
    s16x8 A0[4], A1[4], B0[4], B1[4];
    #pragma unroll
    for (int j = 0; j < 4; ++j) {
      int k = kb + j;
      id[j] = (k < k1) ? myrow[k] : -1;
    }
    #pragma unroll
    for (int j = 0; j < 4; ++j) {
      int k = kb + j;
      int kc = (k < k1) ? k : (k1 - 1);
      const s16x8* r = reinterpret_cast<const s16x8*>(h1b + (size_t)(id[j] < 0 ? 0 : id[j]) * 32);
      A0[j] = r[kq];
      A1[j] = r[2 + kq];
      B0[j] = wb[(size_t)kc * 128 + l];
      B1[j] = wb[(size_t)kc * 128 + 64 + l];
    }
    #pragma unroll
    for (int j = 0; j < 4; ++j) {
      s16x8 a0 = id[j] < 0 ? zv : A0[j];
      s16x8 a1 = id[j] < 0 ? zv : A1[j];
      acc = __builtin_amdgcn_mfma_f32_32x32x16_bf16(a0, B0[j], acc, 0, 0, 0);
      acc = __builtin_amdgcn_mfma_f32_32x32x16_bf16(a1, B1[j], acc, 0, 0, 0);
    }
  }
  __syncthreads();
  float* red = reinterpret_cast<float*>(snbr);
  #pragma unroll
  for (int reg = 0; reg < 16; ++reg) {
    int rrow = (reg & 3) + 8 * (reg >> 2) + 4 * kq;
    red[wave * 1024 + rrow * 32 + col] = acc[reg];
  }
  __syncthreads();
  const f32x4* rv = reinterpret_cast<const f32x4*>(red);
  f32x4 s = rv[tid] + rv[256 + tid] + rv[512 + tid] + rv[768 + tid];
  reinterpret_cast<f32x4*>(h2 + (size_t)pbase * 32)[tid] = s;
}

// ---------------- unary2: out = gelu(LN(h2 @ w2)) + feats  [N,128] f32 ----------------
__global__ __launch_bounds__(256) void unary2_kernel(const float* __restrict__ h2,
    const float* __restrict__ w2, const float* __restrict__ g2,
    const float* __restrict__ b2, const float* __restrict__ feats,
    float* __restrict__ out) {
  int tid = threadIdx.x;
  int wave = tid >> 6;
  int l = tid & 63;
  int r = blockIdx.x * 4 + wave;
  const float* hrow = h2 + (size_t)r * 32;
  float acc0 = 0.f, acc1 = 0.f;
  #pragma unroll
  for (int q = 0; q < 8; ++q) {
    f32x4 hv = reinterpret_cast<const f32x4*>(hrow)[q];
    #pragma unroll
    for (int j = 0; j < 4; ++j) {
      int kk = q * 4 + j;
      float h = hv[j];
      acc0 += h * w2[kk * 128 + l];
      acc1 += h * w2[kk * 128 + 64 + l];
    }
  }
  float s = acc0 + acc1, s2 = acc0 * acc0 + acc1 * acc1;
  #pragma unroll
  for (int m = 32; m >= 1; m >>= 1) {
    s  += __shfl_xor(s,  m, 64);
    s2 += __shfl_xor(s2, m, 64);
  }
  float mean = s * (1.f / 128.f);
  float var  = s2 * (1.f / 128.f) - mean * mean;
  float inv = rsqrtf(var + EPS);
  float y0 = (acc0 - mean) * inv * g2[l] + b2[l];
  float y1 = (acc1 - mean) * inv * g2[64 + l] + b2[64 + l];
  float ge0 = 0.5f * y0 * (1.f + erff(y0 * 0.70710678118f));
  float ge1 = 0.5f * y1 * (1.f + erff(y1 * 0.70710678118f));
  out[(size_t)r * 128 + l]      = ge0 + feats[(size_t)r * 128 + l];
  out[(size_t)r * 128 + 64 + l] = ge1 + feats[(size_t)r * 128 + 64 + l];
}

extern "C" void kernel_launch(void* const* d_in, const int* in_sizes, int n_in,
                              void* d_out, int out_size, void* d_ws, size_t ws_size,
                              hipStream_t stream) {
  const float* feats  = (const float*)d_in[0];
  const int*   nbr    = (const int*)d_in[1];
  const float* w1     = (const float*)d_in[2];
  const float* ln1_g  = (const float*)d_in[3];
  const float* ln1_b  = (const float*)d_in[4];
  const float* w_conv = (const float*)d_in[5];
  const float* w2     = (const float*)d_in[6];
  const float* ln2_g  = (const float*)d_in[7];
  const float* ln2_b  = (const float*)d_in[8];
  float* out = (float*)d_out;
  char* ws = (char*)d_ws;
  bf16*  h1b = (bf16*)ws;                    // 100000*32*2  = 6,400,000 B
  bf16*  wpk = (bf16*)(ws + 6400000);        // 343*128*16   =   702,464 B
  float* h2  = (float*)(ws + 7102464);       // 100000*32*4  = 12,800,000 B
  int*   nbrT = (int*)(ws + 19902464);       // 343*100000*4 = 137,200,000 B
  const size_t need = 19902464ULL + 137200000ULL;

  hipLaunchKernelGGL(pack_kernel,   dim3((KOFF * 128 + 255) / 256), dim3(256), 0, stream, w_conv, wpk);
  hipLaunchKernelGGL(unary1_kernel, dim3(N_PTS / 8),                dim3(256), 0, stream, feats, w1, ln1_g, ln1_b, h1b);
  if (ws_size >= need) {
    hipLaunchKernelGGL(transpose_kernel, dim3((N_PTS + 127) / 128, (KOFF + 31) / 32), dim3(256), 0, stream, nbr, nbrT);
    hipLaunchKernelGGL(conv_t2_kernel,   dim3((NTILES + 1) / 2),                      dim3(256), 0, stream, h1b, nbrT, wpk, h2);
  } else {
    hipLaunchKernelGGL(conv_kernel,      dim3(NTILES),                                dim3(256), 0, stream, h1b, nbr, wpk, h2);
  }
  hipLaunchKernelGGL(unary2_kernel, dim3(N_PTS / 4), dim3(256), 0, stream, h2, w2, ln2_g, ln2_b, feats, out);
}

// Round 6
// 370.027 us; speedup vs baseline: 1.2796x; 1.2319x over previous
//
#include <hip/hip_runtime.h>
#include <hip/hip_bf16.h>

#define N_PTS 100000
#define KOFF 343
#define EPS 1e-5f
#define NTILES 3125   // N_PTS / 32

typedef __hip_bfloat16 bf16;
typedef __attribute__((ext_vector_type(4))) float f32x4;
typedef __attribute__((ext_vector_type(16))) float f32x16;
typedef __attribute__((ext_vector_type(8))) short s16x8;

// ---------------- pack: w_conv [343][32][32] f32 -> bf16 B-fragments ----------------
// wpk layout: [k][s][lane][j], element = w_conv[k][s*16 + (lane>>5)*8 + j][lane&31]
__global__ __launch_bounds__(256) void pack_kernel(const float* __restrict__ w_conv,
                                                   bf16* __restrict__ wpk) {
  int t = blockIdx.x * 256 + threadIdx.x;
  if (t >= KOFF * 128) return;
  int l = t & 63;
  int s = (t >> 6) & 1;
  int k = t >> 7;
  int col = l & 31;
  int kq = l >> 5;
  const float* wk = w_conv + k * 1024;
  s16x8 v;
  for (int j = 0; j < 8; ++j) {
    bf16 h = __float2bfloat16(wk[(s * 16 + kq * 8 + j) * 32 + col]);
    short sv;
    __builtin_memcpy(&sv, &h, 2);
    v[j] = sv;
  }
  *reinterpret_cast<s16x8*>(reinterpret_cast<char*>(wpk) + (size_t)t * 16) = v;
}

// ---------------- unary1: h1b = bf16( LN(feats @ w1) )  [N,32]; also zeroes row N ----------------
__global__ __launch_bounds__(256) void unary1_kernel(const float* __restrict__ feats,
    const float* __restrict__ w1, const float* __restrict__ g1,
    const float* __restrict__ b1, bf16* __restrict__ h1b) {
  __shared__ float sf[8][128];
  __shared__ float sw[128 * 32];
  int tid = threadIdx.x;
  int rbase = blockIdx.x * 8;
  if (blockIdx.x == 0 && tid < 16)
    reinterpret_cast<int*>(h1b)[N_PTS * 16 + tid] = 0;   // zero row for invalid nbrs
  for (int i = tid; i < 1024; i += 256)
    reinterpret_cast<f32x4*>(sw)[i] = reinterpret_cast<const f32x4*>(w1)[i];
  {
    int i = tid;
    int r = rbase + (i >> 5);
    f32x4 v = reinterpret_cast<const f32x4*>(feats)[(size_t)r * 32 + (i & 31)];
    reinterpret_cast<f32x4*>(&sf[0][0])[i] = v;
  }
  __syncthreads();
  int half = tid >> 5;
  int c = tid & 31;
  int r = rbase + half;
  const float* frow = sf[half];
  float acc = 0.f;
  #pragma unroll 8
  for (int kk = 0; kk < 128; ++kk)
    acc += frow[kk] * sw[kk * 32 + c];
  float s = acc, s2 = acc * acc;
  #pragma unroll
  for (int m = 16; m >= 1; m >>= 1) {
    s  += __shfl_xor(s,  m, 64);
    s2 += __shfl_xor(s2, m, 64);
  }
  float mean = s * (1.f / 32.f);
  float var  = s2 * (1.f / 32.f) - mean * mean;
  float y = (acc - mean) * rsqrtf(var + EPS) * g1[c] + b1[c];
  h1b[(size_t)r * 32 + c] = __float2bfloat16(y);
}

// ---------------- conv: 4 staging rounds, k-split x4, LDS-resident idx ----------------
// Block = 256 thr = 4 waves, one 32-point tile. Per round: stage 32x~86 idx (11 KB,
// coalesced, -1 translated to zero-row N_PTS) -> each wave processes its quarter of
// the round's offsets. LDS = 16 KB (staging buf reused for reduction) -> 8 blocks/CU.
// A-frag: row=lane&31, kq=lane>>5; D: col=lane&31, row=(reg&3)+8*(reg>>2)+4*kq
#define SSTRIDE 87

template<int KCNT, int KBASE>
__device__ __forceinline__ void stage_round(const int* __restrict__ g,
                                            int* __restrict__ snbr, int tid) {
  for (int i = tid; i < 32 * KCNT; i += 256) {
    int row = i / KCNT;                 // const divisor -> magic mul
    int kk = i - row * KCNT;
    int v = g[row * KOFF + KBASE + kk];
    snbr[row * SSTRIDE + kk] = v < 0 ? N_PTS : v;
  }
}

template<int KCNT, int KBASE>
__device__ __forceinline__ void process_round(const int* __restrict__ snbr,
    const bf16* __restrict__ h1b, const s16x8* __restrict__ wb,
    f32x16& acc, int wave, int l, int col, int kq) {
  int k0 = (KCNT * wave) >> 2;
  int k1 = (KCNT * (wave + 1)) >> 2;
  const int* myrow = snbr + col * SSTRIDE;
  int id0 = myrow[k0];
  int id1 = (k0 + 1 < k1) ? myrow[k0 + 1] : N_PTS;
  for (int kb = k0; kb < k1; kb += 2) {
    // prefetch next chunk's idx from LDS (hidden under gathers+MFMA)
    int idn0 = (kb + 2 < k1) ? myrow[kb + 2] : N_PTS;
    int idn1 = (kb + 3 < k1) ? myrow[kb + 3] : N_PTS;
    const s16x8* r0 = reinterpret_cast<const s16x8*>(h1b + (size_t)id0 * 32);
    const s16x8* r1 = reinterpret_cast<const s16x8*>(h1b + (size_t)id1 * 32);
    s16x8 A00 = r0[kq], A01 = r0[2 + kq];
    s16x8 A10 = r1[kq], A11 = r1[2 + kq];
    int kg0 = KBASE + kb;
    int kg1 = KBASE + ((kb + 1 < k1) ? kb + 1 : kb);   // tail: A1x==0 anyway
    s16x8 B00 = wb[(size_t)kg0 * 128 + l];
    s16x8 B01 = wb[(size_t)kg0 * 128 + 64 + l];
    s16x8 B10 = wb[(size_t)kg1 * 128 + l];
    s16x8 B11 = wb[(size_t)kg1 * 128 + 64 + l];
    acc = __builtin_amdgcn_mfma_f32_32x32x16_bf16(A00, B00, acc, 0, 0, 0);
    acc = __builtin_amdgcn_mfma_f32_32x32x16_bf16(A01, B01, acc, 0, 0, 0);
    acc = __builtin_amdgcn_mfma_f32_32x32x16_bf16(A10, B10, acc, 0, 0, 0);
    acc = __builtin_amdgcn_mfma_f32_32x32x16_bf16(A11, B11, acc, 0, 0, 0);
    id0 = idn0; id1 = idn1;
  }
}

__global__ __launch_bounds__(256, 8) void conv_s_kernel(const bf16* __restrict__ h1b,
    const int* __restrict__ nbr, const bf16* __restrict__ wpk,
    float* __restrict__ h2) {
  __shared__ int snbr[4096];              // 16 KB: staging (2784 ints) + reduction reuse
  int tid = threadIdx.x;
  int wave = tid >> 6;
  int l = tid & 63;
  int col = l & 31;
  int kq = l >> 5;
  int pbase = blockIdx.x * 32;
  const int* g = nbr + (size_t)pbase * KOFF;
  const s16x8* wb = reinterpret_cast<const s16x8*>(wpk);
  f32x16 acc;
  #pragma unroll
  for (int i = 0; i < 16; ++i) acc[i] = 0.f;

  stage_round<86, 0>(g, snbr, tid);
  __syncthreads();
  process_round<86, 0>(snbr, h1b, wb, acc, wave, l, col, kq);
  __syncthreads();
  stage_round<86, 86>(g, snbr, tid);
  __syncthreads();
  process_round<86, 86>(snbr, h1b, wb, acc, wave, l, col, kq);
  __syncthreads();
  stage_round<86, 172>(g, snbr, tid);
  __syncthreads();
  process_round<86, 172>(snbr, h1b, wb, acc, wave, l, col, kq);
  __syncthreads();
  stage_round<85, 258>(g, snbr, tid);
  __syncthreads();
  process_round<85, 258>(snbr, h1b, wb, acc, wave, l, col, kq);
  __syncthreads();

  float* red = reinterpret_cast<float*>(snbr);
  #pragma unroll
  for (int reg = 0; reg < 16; ++reg) {
    int rrow = (reg & 3) + 8 * (reg >> 2) + 4 * kq;
    red[wave * 1024 + rrow * 32 + col] = acc[reg];
  }
  __syncthreads();
  const f32x4* rv = reinterpret_cast<const f32x4*>(red);
  f32x4 s = rv[tid] + rv[256 + tid] + rv[512 + tid] + rv[768 + tid];
  reinterpret_cast<f32x4*>(h2 + (size_t)pbase * 32)[tid] = s;
}

// ---------------- unary2: out = gelu(LN(h2 @ w2)) + feats  [N,128] f32 ----------------
__global__ __launch_bounds__(256) void unary2_kernel(const float* __restrict__ h2,
    const float* __restrict__ w2, const float* __restrict__ g2,
    const float* __restrict__ b2, const float* __restrict__ feats,
    float* __restrict__ out) {
  int tid = threadIdx.x;
  int wave = tid >> 6;
  int l = tid & 63;
  int r = blockIdx.x * 4 + wave;
  const float* hrow = h2 + (size_t)r * 32;
  float acc0 = 0.f, acc1 = 0.f;
  #pragma unroll
  for (int q = 0; q < 8; ++q) {
    f32x4 hv = reinterpret_cast<const f32x4*>(hrow)[q];
    #pragma unroll
    for (int j = 0; j < 4; ++j) {
      int kk = q * 4 + j;
      float h = hv[j];
      acc0 += h * w2[kk * 128 + l];
      acc1 += h * w2[kk * 128 + 64 + l];
    }
  }
  float s = acc0 + acc1, s2 = acc0 * acc0 + acc1 * acc1;
  #pragma unroll
  for (int m = 32; m >= 1; m >>= 1) {
    s  += __shfl_xor(s,  m, 64);
    s2 += __shfl_xor(s2, m, 64);
  }
  float mean = s * (1.f / 128.f);
  float var  = s2 * (1.f / 128.f) - mean * mean;
  float inv = rsqrtf(var + EPS);
  float y0 = (acc0 - mean) * inv * g2[l] + b2[l];
  float y1 = (acc1 - mean) * inv * g2[64 + l] + b2[64 + l];
  float ge0 = 0.5f * y0 * (1.f + erff(y0 * 0.70710678118f));
  float ge1 = 0.5f * y1 * (1.f + erff(y1 * 0.70710678118f));
  out[(size_t)r * 128 + l]      = ge0 + feats[(size_t)r * 128 + l];
  out[(size_t)r * 128 + 64 + l] = ge1 + feats[(size_t)r * 128 + 64 + l];
}

extern "C" void kernel_launch(void* const* d_in, const int* in_sizes, int n_in,
                              void* d_out, int out_size, void* d_ws, size_t ws_size,
                              hipStream_t stream) {
  const float* feats  = (const float*)d_in[0];
  const int*   nbr    = (const int*)d_in[1];
  const float* w1     = (const float*)d_in[2];
  const float* ln1_g  = (const float*)d_in[3];
  const float* ln1_b  = (const float*)d_in[4];
  const float* w_conv = (const float*)d_in[5];
  const float* w2     = (const float*)d_in[6];
  const float* ln2_g  = (const float*)d_in[7];
  const float* ln2_b  = (const float*)d_in[8];
  float* out = (float*)d_out;
  char* ws = (char*)d_ws;
  bf16*  h1b = (bf16*)ws;                    // (100000+1)*32*2 = 6,400,064 B (row N = zeros)
  bf16*  wpk = (bf16*)(ws + 6400064);        // 343*128*16      =   702,464 B
  float* h2  = (float*)(ws + 7102528);       // 100000*32*4     = 12,800,000 B

  hipLaunchKernelGGL(pack_kernel,   dim3((KOFF * 128 + 255) / 256), dim3(256), 0, stream, w_conv, wpk);
  hipLaunchKernelGGL(unary1_kernel, dim3(N_PTS / 8),                dim3(256), 0, stream, feats, w1, ln1_g, ln1_b, h1b);
  hipLaunchKernelGGL(conv_s_kernel, dim3(NTILES),                   dim3(256), 0, stream, h1b, nbr, wpk, h2);
  hipLaunchKernelGGL(unary2_kernel, dim3(N_PTS / 4),                dim3(256), 0, stream, h2, w2, ln2_g, ln2_b, feats, out);
}